// Round 3
// baseline (326.681 us; speedup 1.0000x reference)
//
#include <hip/hip_runtime.h>
#include <stdint.h>

// Problem constants (fixed by setup_inputs): B=8192, I=512, H=1024
#define BATCH 8192
#define IDIM  512
#define HDIM  1024
#define KDIM  1536          // I + H
#define NDIM  4096          // 4*H

typedef __bf16 bf16x8 __attribute__((ext_vector_type(8)));
typedef float  f32x4  __attribute__((ext_vector_type(4)));
typedef unsigned short u16x8 __attribute__((ext_vector_type(8)));

__device__ __forceinline__ unsigned short f2bf(float f) {
    union { float f; unsigned u; } v; v.f = f;
    unsigned r = v.u + 0x7fffu + ((v.u >> 16) & 1u);   // RNE
    return (unsigned short)(r >> 16);
}
__device__ __forceinline__ float bf2f(unsigned short u) {
    union { unsigned u; float f; } v; v.u = ((unsigned)u) << 16;
    return v.f;
}
__device__ __forceinline__ float fexp(float x) {      // e^x via v_exp_f32
    return __builtin_amdgcn_exp2f(x * 1.44269504f);
}
__device__ __forceinline__ float sigm(float x) {      // stable for |x| large
    return __builtin_amdgcn_rcpf(1.f + fexp(-x));
}
__device__ __forceinline__ float ftanh(float x) {     // 1 - 2/(e^{2x}+1)
    return 1.f - 2.f * __builtin_amdgcn_rcpf(1.f + fexp(2.f * x));
}

__device__ __forceinline__ void load16(void* lds, const void* g) {
    __builtin_amdgcn_global_load_lds(
        (const __attribute__((address_space(1))) unsigned int*)g,
        (__attribute__((address_space(3))) unsigned int*)lds, 16, 0, 0);
}

// ------------- Kernel 1: fused input packing ------------------------------
// blocks [0, NPACKA): pack [x|h] -> bf16 A (BATCH x KDIM)
// blocks [NPACKA, ..): transpose+convert [Wi;Wh] -> bf16 Wt (NDIM x KDIM)
#define NPACKA (BATCH * KDIM / 4 / 256)      // 12288
#define NPACKW ((NDIM / 32) * (KDIM / 32))   // 6144
__global__ __launch_bounds__(256) void pack_ab(const float* __restrict__ x,
                                               const float* __restrict__ h,
                                               const float* __restrict__ Wi,
                                               const float* __restrict__ Wh,
                                               unsigned short* __restrict__ A,
                                               unsigned short* __restrict__ Wt) {
    __shared__ float tile[32][33];
    int blk = blockIdx.x;
    if (blk < NPACKA) {
        int idx = blk * 256 + threadIdx.x;   // group of 4 elements
        int row = idx / (KDIM / 4);
        int g   = idx % (KDIM / 4);
        int col = g * 4;
        float4 v;
        if (col < IDIM) v = ((const float4*)(x + (size_t)row * IDIM))[g];
        else            v = ((const float4*)(h + (size_t)row * HDIM))[(col - IDIM) / 4];
        ushort4 o;
        o.x = f2bf(v.x); o.y = f2bf(v.y); o.z = f2bf(v.z); o.w = f2bf(v.w);
        ((ushort4*)A)[idx] = o;
    } else {
        int b  = blk - NPACKA;
        int n0 = (b & 127) * 32;             // column in W  (0..NDIM)
        int k0 = (b >> 7) * 32;              // row in W     (0..KDIM)
        int tx = threadIdx.x & 31, ty = threadIdx.x >> 5;   // 32 x 8
#pragma unroll
        for (int j = 0; j < 4; j++) {
            int k = k0 + ty + 8 * j;
            float v;
            if (k < IDIM) v = Wi[(size_t)k * NDIM + n0 + tx];
            else          v = Wh[(size_t)(k - IDIM) * NDIM + n0 + tx];
            tile[ty + 8 * j][tx] = v;
        }
        __syncthreads();
#pragma unroll
        for (int j = 0; j < 4; j++)
            Wt[(size_t)(n0 + ty + 8 * j) * KDIM + k0 + tx] = f2bf(tile[tx][ty + 8 * j]);
    }
}

// ---------------- Kernel 2: bf16 GEMM gates = A @ Wt^T (bf16 out) ----------
// 128x128 block tile, BK=32, 4 waves each doing 4x4 mfma_f32_16x16x32_bf16.
// LDS k-chunk position XOR-swizzled by (row>>1)&3 (conflict-free ds_read_b128).
// Grid is N-fastest: consecutive blocks share the A-tile; Wt working set
// (12.6 MB) stays L3/L2-resident across the resident-block window.
__global__ __launch_bounds__(256) void gemm_bt(const unsigned short* __restrict__ A,
                                               const unsigned short* __restrict__ Bt,
                                               unsigned short* __restrict__ C) {
    __shared__ __align__(16) unsigned short sA[128 * 32];
    __shared__ __align__(16) unsigned short sB[128 * 32];

    const int t    = threadIdx.x;
    const int wave = t >> 6;
    const int lane = t & 63;
    const int bn   = blockIdx.x * 128;
    const int bm   = blockIdx.y * 128;

    const int wm   = (wave & 1) * 64;
    const int wn   = (wave >> 1) * 64;
    const int lrow = lane & 15;
    const int quad = lane >> 4;

    f32x4 acc[4][4] = {};

    // staging: call s writes LDS chunk i = s*256 + t (16B chunks);
    // source chunk for LDS slot i: row = i>>2, kc = (i&3) ^ ((row>>1)&3)
    const int r0 = t >> 2,        p0 = t & 3;
    const int k0c = p0 ^ ((r0 >> 1) & 3);
    const int r1 = (256 + t) >> 2, p1 = t & 3;
    const int k1c = p1 ^ ((r1 >> 1) & 3);
    const unsigned short* a0p = A  + (size_t)(bm + r0) * KDIM + k0c * 8;
    const unsigned short* a1p = A  + (size_t)(bm + r1) * KDIM + k1c * 8;
    const unsigned short* b0p = Bt + (size_t)(bn + r0) * KDIM + k0c * 8;
    const unsigned short* b1p = Bt + (size_t)(bn + r1) * KDIM + k1c * 8;

    // fragment-read offsets (shorts), constant over k
    int aoff[4], boff[4];
#pragma unroll
    for (int i = 0; i < 4; i++) {
        int ra = wm + i * 16 + lrow;
        aoff[i] = ra * 32 + (quad ^ ((ra >> 1) & 3)) * 8;
        int rb = wn + i * 16 + lrow;
        boff[i] = rb * 32 + (quad ^ ((rb >> 1) & 3)) * 8;
    }

    for (int k0 = 0; k0 < KDIM; k0 += 32) {
        load16(sA + 0 * 2048 + wave * 512, a0p + k0);
        load16(sB + 0 * 2048 + wave * 512, b0p + k0);
        load16(sA + 1 * 2048 + wave * 512, a1p + k0);
        load16(sB + 1 * 2048 + wave * 512, b1p + k0);
        __syncthreads();

        bf16x8 af[4], bf[4];
#pragma unroll
        for (int mt = 0; mt < 4; mt++) af[mt] = *(const bf16x8*)(sA + aoff[mt]);
#pragma unroll
        for (int nt = 0; nt < 4; nt++) bf[nt] = *(const bf16x8*)(sB + boff[nt]);
#pragma unroll
        for (int mt = 0; mt < 4; mt++)
#pragma unroll
            for (int nt = 0; nt < 4; nt++)
                acc[mt][nt] = __builtin_amdgcn_mfma_f32_16x16x32_bf16(
                    af[mt], bf[nt], acc[mt][nt], 0, 0, 0);
        __syncthreads();
    }

#pragma unroll
    for (int mt = 0; mt < 4; mt++) {
#pragma unroll
        for (int nt = 0; nt < 4; nt++) {
            int row = bm + wm + mt * 16 + quad * 4;
            int col = bn + wn + nt * 16 + lrow;
#pragma unroll
            for (int r = 0; r < 4; r++)
                C[(size_t)(row + r) * NDIM + col] = f2bf(acc[mt][nt][r]);
        }
    }
}

// ---------------- Kernel 3: per-row LN + LSTM epilogue ---------------------
// One WAVE per batch row (4 rows/block). Lane l owns columns [16l,16l+16) of
// all 4 gates -> the 4 LN reductions are full-wave shuffle reductions and the
// i/f/g/o combine is intra-lane. No LDS, no __syncthreads.
__global__ __launch_bounds__(256) void lstm_ep(const unsigned short* __restrict__ gates,
                                               const float* __restrict__ bh,
                                               const float* __restrict__ c,
                                               const float* __restrict__ gamma,
                                               const float* __restrict__ beta,
                                               float* __restrict__ out) {
    const int wave = threadIdx.x >> 6;
    const int lane = threadIdx.x & 63;
    const int b    = blockIdx.x * 4 + wave;
    const int col0 = lane * 16;

    const unsigned short* gr = gates + (size_t)b * NDIM;
    float v[4][16];
    float s[4], sq[4];
#pragma unroll
    for (int g = 0; g < 4; g++) {
        const unsigned short* gp = gr + g * HDIM + col0;
        u16x8 ga = *(const u16x8*)gp;
        u16x8 gb = *(const u16x8*)(gp + 8);
        float bb[16];
#pragma unroll
        for (int q = 0; q < 4; q++)
            *(float4*)(bb + 4 * q) = ((const float4*)(bh + g * HDIM + col0))[q];
        float ls = 0.f, lq = 0.f;
#pragma unroll
        for (int j = 0; j < 16; j++) {
            float tv = bf2f(j < 8 ? ga[j] : gb[j - 8]) + bb[j];
            v[g][j] = tv; ls += tv; lq += tv * tv;
        }
        s[g] = ls; sq[g] = lq;
    }
#pragma unroll
    for (int off = 32; off; off >>= 1) {
#pragma unroll
        for (int g = 0; g < 4; g++) {
            s[g]  += __shfl_xor(s[g], off);
            sq[g] += __shfl_xor(sq[g], off);
        }
    }
#pragma unroll
    for (int g = 0; g < 4; g++) {
        const float mu  = s[g] * (1.f / HDIM);
        const float var = sq[g] * (1.f / HDIM) - mu * mu;
        const float rs  = rsqrtf(var + 1e-5f);
        float gm[16], bt[16];
#pragma unroll
        for (int q = 0; q < 4; q++) {
            *(float4*)(gm + 4 * q) = ((const float4*)(gamma + g * HDIM + col0))[q];
            *(float4*)(bt + 4 * q) = ((const float4*)(beta  + g * HDIM + col0))[q];
        }
#pragma unroll
        for (int j = 0; j < 16; j++) {
            float y = (v[g][j] - mu) * rs * gm[j] + bt[j];
            v[g][j] = (g == 2) ? ftanh(y) : sigm(y);
        }
    }
    const size_t base = (size_t)b * HDIM + col0;
#pragma unroll
    for (int q = 0; q < 4; q++) {
        float4 ci = *(const float4*)(c + base + 4 * q);
        float4 cn, hn;
#pragma unroll
        for (int e = 0; e < 4; e++) {
            int j = 4 * q + e;
            float cnv = v[1][j] * ((float*)&ci)[e] + v[0][j] * v[2][j];
            ((float*)&cn)[e] = cnv;
            ((float*)&hn)[e] = v[3][j] * ftanh(cnv);
        }
        *(float4*)(out + base + 4 * q) = hn;                               // h_new
        *(float4*)(out + (size_t)BATCH * HDIM + base + 4 * q) = cn;        // c_new
    }
}

extern "C" void kernel_launch(void* const* d_in, const int* in_sizes, int n_in,
                              void* d_out, int out_size, void* d_ws, size_t ws_size,
                              hipStream_t stream) {
    const float* x     = (const float*)d_in[0];
    const float* h     = (const float*)d_in[1];
    const float* c     = (const float*)d_in[2];
    const float* Wi    = (const float*)d_in[3];
    const float* Wh    = (const float*)d_in[4];
    const float* bh    = (const float*)d_in[5];
    const float* gamma = (const float*)d_in[6];
    const float* beta  = (const float*)d_in[7];
    float* out = (float*)d_out;

    // workspace layout
    unsigned short* A  = (unsigned short*)d_ws;                                        // 25.2 MB
    unsigned short* Wt = (unsigned short*)((char*)d_ws + (size_t)BATCH * KDIM * 2);    // 12.6 MB
    unsigned short* gates = (unsigned short*)((char*)d_ws + (size_t)BATCH * KDIM * 2
                                                          + (size_t)NDIM * KDIM * 2); // 64 MB

    pack_ab<<<NPACKA + NPACKW, 256, 0, stream>>>(x, h, Wi, Wh, A, Wt);
    gemm_bt<<<dim3(NDIM / 128, BATCH / 128), 256, 0, stream>>>(A, Wt, gates);
    lstm_ep<<<BATCH / 4, 256, 0, stream>>>(gates, bh, c, gamma, beta, out);
}

// Round 4
// 315.019 us; speedup vs baseline: 1.0370x; 1.0370x over previous
//
#include <hip/hip_runtime.h>
#include <stdint.h>

// Problem constants (fixed by setup_inputs): B=8192, I=512, H=1024
#define BATCH 8192
#define IDIM  512
#define HDIM  1024
#define KDIM  1536          // I + H
#define NDIM  4096          // 4*H
#define BK    64            // GEMM K-tile (halves barrier count vs 32)

typedef __bf16 bf16x8 __attribute__((ext_vector_type(8)));
typedef float  f32x4  __attribute__((ext_vector_type(4)));
typedef unsigned short u16x8 __attribute__((ext_vector_type(8)));

__device__ __forceinline__ unsigned short f2bf(float f) {
    union { float f; unsigned u; } v; v.f = f;
    unsigned r = v.u + 0x7fffu + ((v.u >> 16) & 1u);   // RNE
    return (unsigned short)(r >> 16);
}
__device__ __forceinline__ float bf2f(unsigned short u) {
    union { unsigned u; float f; } v; v.u = ((unsigned)u) << 16;
    return v.f;
}
__device__ __forceinline__ float fexp(float x) {      // e^x via v_exp_f32
    return __builtin_amdgcn_exp2f(x * 1.44269504f);
}
__device__ __forceinline__ float sigm(float x) {      // stable for |x| large
    return __builtin_amdgcn_rcpf(1.f + fexp(-x));
}
__device__ __forceinline__ float ftanh(float x) {     // 1 - 2/(e^{2x}+1)
    return 1.f - 2.f * __builtin_amdgcn_rcpf(1.f + fexp(2.f * x));
}

__device__ __forceinline__ void load16(void* lds, const void* g) {
    __builtin_amdgcn_global_load_lds(
        (const __attribute__((address_space(1))) unsigned int*)g,
        (__attribute__((address_space(3))) unsigned int*)lds, 16, 0, 0);
}

// ------------- Kernel 1: fused input packing ------------------------------
// blocks [0, NPACKA): pack [x|h] -> bf16 A (BATCH x KDIM)
// blocks [NPACKA, ..): transpose+convert [Wi;Wh] -> bf16 Wt (NDIM x KDIM)
#define NPACKA (BATCH * KDIM / 4 / 256)      // 12288
#define NPACKW ((NDIM / 32) * (KDIM / 32))   // 6144
__global__ __launch_bounds__(256) void pack_ab(const float* __restrict__ x,
                                               const float* __restrict__ h,
                                               const float* __restrict__ Wi,
                                               const float* __restrict__ Wh,
                                               unsigned short* __restrict__ A,
                                               unsigned short* __restrict__ Wt) {
    __shared__ float tile[32][33];
    int blk = blockIdx.x;
    if (blk < NPACKA) {
        int idx = blk * 256 + threadIdx.x;   // group of 4 elements
        int row = idx / (KDIM / 4);
        int g   = idx % (KDIM / 4);
        int col = g * 4;
        float4 v;
        if (col < IDIM) v = ((const float4*)(x + (size_t)row * IDIM))[g];
        else            v = ((const float4*)(h + (size_t)row * HDIM))[(col - IDIM) / 4];
        ushort4 o;
        o.x = f2bf(v.x); o.y = f2bf(v.y); o.z = f2bf(v.z); o.w = f2bf(v.w);
        ((ushort4*)A)[idx] = o;
    } else {
        int b  = blk - NPACKA;
        int n0 = (b & 127) * 32;             // column in W  (0..NDIM)
        int k0 = (b >> 7) * 32;              // row in W     (0..KDIM)
        int tx = threadIdx.x & 31, ty = threadIdx.x >> 5;   // 32 x 8
#pragma unroll
        for (int j = 0; j < 4; j++) {
            int k = k0 + ty + 8 * j;
            float v;
            if (k < IDIM) v = Wi[(size_t)k * NDIM + n0 + tx];
            else          v = Wh[(size_t)(k - IDIM) * NDIM + n0 + tx];
            tile[ty + 8 * j][tx] = v;
        }
        __syncthreads();
#pragma unroll
        for (int j = 0; j < 4; j++)
            Wt[(size_t)(n0 + ty + 8 * j) * KDIM + k0 + tx] = f2bf(tile[tx][ty + 8 * j]);
    }
}

// ---------------- Kernel 2: bf16 GEMM gates = A @ Wt^T (bf16 out) ----------
// 128x128 block tile, BK=64 (24 LDS stages instead of 48 -> half the barrier
// drains), 4 waves each doing 4x4 mfma_f32_16x16x32_bf16 over 2 k-substeps.
// LDS k-chunk position XOR-swizzled by (row&7): staging rows stay contiguous
// 128B reads (permutation within row); ds_read_b128 fragment phases hit each
// of the 8 bank-groups exactly 2x (2-way = free, m136).
// Grid M-fastest (R2 config): FETCH was 86MB vs 117MB N-fastest.
__global__ __launch_bounds__(256) void gemm_bt(const unsigned short* __restrict__ A,
                                               const unsigned short* __restrict__ Bt,
                                               unsigned short* __restrict__ C) {
    __shared__ __align__(16) unsigned short sA[128 * BK];   // 16 KB
    __shared__ __align__(16) unsigned short sB[128 * BK];   // 16 KB

    const int t    = threadIdx.x;
    const int wave = t >> 6;
    const int lane = t & 63;
    const int bm   = blockIdx.x * 128;
    const int bn   = blockIdx.y * 128;

    const int wm   = (wave & 1) * 64;
    const int wn   = (wave >> 1) * 64;
    const int lrow = lane & 15;
    const int quad = lane >> 4;

    f32x4 acc[4][4] = {};

    // staging: call s (0..3) writes 16B LDS chunk i = s*256 + t;
    // row = i>>3, pos = i&7, source k-chunk kc = pos ^ (row&7)
    int aofs[4], bofs[4];
#pragma unroll
    for (int s = 0; s < 4; s++) {
        int i = s * 256 + t;
        int r = i >> 3, pos = i & 7;
        int kc = pos ^ (r & 7);
        aofs[s] = (bm + r) * KDIM + kc * 8;
        bofs[s] = (bn + r) * KDIM + kc * 8;
    }

    // fragment-read offsets (shorts), constant over k: substep ss, tile i
    int aoff[2][4], boff[2][4];
#pragma unroll
    for (int ss = 0; ss < 2; ss++)
#pragma unroll
        for (int i = 0; i < 4; i++) {
            int ra = wm + i * 16 + lrow;
            aoff[ss][i] = ra * BK + ((quad + 4 * ss) ^ (ra & 7)) * 8;
            int rb = wn + i * 16 + lrow;
            boff[ss][i] = rb * BK + ((quad + 4 * ss) ^ (rb & 7)) * 8;
        }

    for (int k0 = 0; k0 < KDIM; k0 += BK) {
#pragma unroll
        for (int s = 0; s < 4; s++) {
            load16(sA + s * 2048 + t * 8, A + (size_t)aofs[s] + k0);
            load16(sB + s * 2048 + t * 8, Bt + (size_t)bofs[s] + k0);
        }
        __syncthreads();

#pragma unroll
        for (int ss = 0; ss < 2; ss++) {
            bf16x8 af[4], bf[4];
#pragma unroll
            for (int mt = 0; mt < 4; mt++) af[mt] = *(const bf16x8*)(sA + aoff[ss][mt]);
#pragma unroll
            for (int nt = 0; nt < 4; nt++) bf[nt] = *(const bf16x8*)(sB + boff[ss][nt]);
#pragma unroll
            for (int mt = 0; mt < 4; mt++)
#pragma unroll
                for (int nt = 0; nt < 4; nt++)
                    acc[mt][nt] = __builtin_amdgcn_mfma_f32_16x16x32_bf16(
                        af[mt], bf[nt], acc[mt][nt], 0, 0, 0);
        }
        __syncthreads();
    }

#pragma unroll
    for (int mt = 0; mt < 4; mt++) {
#pragma unroll
        for (int nt = 0; nt < 4; nt++) {
            int row = bm + wm + mt * 16 + quad * 4;
            int col = bn + wn + nt * 16 + lrow;
#pragma unroll
            for (int r = 0; r < 4; r++)
                C[(size_t)(row + r) * NDIM + col] = f2bf(acc[mt][nt][r]);
        }
    }
}

// ---------------- Kernel 3: per-row LN + LSTM epilogue ---------------------
// One WAVE per batch row (4 rows/block). Lane l owns columns [16l,16l+16) of
// all 4 gates -> the 4 LN reductions are full-wave shuffle reductions and the
// i/f/g/o combine is intra-lane. No LDS, no __syncthreads.
__global__ __launch_bounds__(256) void lstm_ep(const unsigned short* __restrict__ gates,
                                               const float* __restrict__ bh,
                                               const float* __restrict__ c,
                                               const float* __restrict__ gamma,
                                               const float* __restrict__ beta,
                                               float* __restrict__ out) {
    const int wave = threadIdx.x >> 6;
    const int lane = threadIdx.x & 63;
    const int b    = blockIdx.x * 4 + wave;
    const int col0 = lane * 16;

    const unsigned short* gr = gates + (size_t)b * NDIM;
    float v[4][16];
    float s[4], sq[4];
#pragma unroll
    for (int g = 0; g < 4; g++) {
        const unsigned short* gp = gr + g * HDIM + col0;
        u16x8 ga = *(const u16x8*)gp;
        u16x8 gb = *(const u16x8*)(gp + 8);
        float bb[16];
#pragma unroll
        for (int q = 0; q < 4; q++)
            *(float4*)(bb + 4 * q) = ((const float4*)(bh + g * HDIM + col0))[q];
        float ls = 0.f, lq = 0.f;
#pragma unroll
        for (int j = 0; j < 16; j++) {
            float tv = bf2f(j < 8 ? ga[j] : gb[j - 8]) + bb[j];
            v[g][j] = tv; ls += tv; lq += tv * tv;
        }
        s[g] = ls; sq[g] = lq;
    }
#pragma unroll
    for (int off = 32; off; off >>= 1) {
#pragma unroll
        for (int g = 0; g < 4; g++) {
            s[g]  += __shfl_xor(s[g], off);
            sq[g] += __shfl_xor(sq[g], off);
        }
    }
#pragma unroll
    for (int g = 0; g < 4; g++) {
        const float mu  = s[g] * (1.f / HDIM);
        const float var = sq[g] * (1.f / HDIM) - mu * mu;
        const float rs  = rsqrtf(var + 1e-5f);
        float gm[16], bt[16];
#pragma unroll
        for (int q = 0; q < 4; q++) {
            *(float4*)(gm + 4 * q) = ((const float4*)(gamma + g * HDIM + col0))[q];
            *(float4*)(bt + 4 * q) = ((const float4*)(beta  + g * HDIM + col0))[q];
        }
#pragma unroll
        for (int j = 0; j < 16; j++) {
            float y = (v[g][j] - mu) * rs * gm[j] + bt[j];
            v[g][j] = (g == 2) ? ftanh(y) : sigm(y);
        }
    }
    const size_t base = (size_t)b * HDIM + col0;
#pragma unroll
    for (int q = 0; q < 4; q++) {
        float4 ci = *(const float4*)(c + base + 4 * q);
        float4 cn, hn;
#pragma unroll
        for (int e = 0; e < 4; e++) {
            int j = 4 * q + e;
            float cnv = v[1][j] * ((float*)&ci)[e] + v[0][j] * v[2][j];
            ((float*)&cn)[e] = cnv;
            ((float*)&hn)[e] = v[3][j] * ftanh(cnv);
        }
        *(float4*)(out + base + 4 * q) = hn;                               // h_new
        *(float4*)(out + (size_t)BATCH * HDIM + base + 4 * q) = cn;        // c_new
    }
}

extern "C" void kernel_launch(void* const* d_in, const int* in_sizes, int n_in,
                              void* d_out, int out_size, void* d_ws, size_t ws_size,
                              hipStream_t stream) {
    const float* x     = (const float*)d_in[0];
    const float* h     = (const float*)d_in[1];
    const float* c     = (const float*)d_in[2];
    const float* Wi    = (const float*)d_in[3];
    const float* Wh    = (const float*)d_in[4];
    const float* bh    = (const float*)d_in[5];
    const float* gamma = (const float*)d_in[6];
    const float* beta  = (const float*)d_in[7];
    float* out = (float*)d_out;

    // workspace layout
    unsigned short* A  = (unsigned short*)d_ws;                                        // 25.2 MB
    unsigned short* Wt = (unsigned short*)((char*)d_ws + (size_t)BATCH * KDIM * 2);    // 12.6 MB
    unsigned short* gates = (unsigned short*)((char*)d_ws + (size_t)BATCH * KDIM * 2
                                                          + (size_t)NDIM * KDIM * 2); // 64 MB

    pack_ab<<<NPACKA + NPACKW, 256, 0, stream>>>(x, h, Wi, Wh, A, Wt);
    gemm_bt<<<dim3(BATCH / 128, NDIM / 128), 256, 0, stream>>>(A, Wt, gates);
    lstm_ep<<<BATCH / 4, 256, 0, stream>>>(gates, bh, c, gamma, beta, out);
}